// Round 9
// baseline (181.889 us; speedup 1.0000x reference)
//
#include <hip/hip_runtime.h>
#include <stdint.h>

#define N_SPK 2048
#define M_UTT 16
#define D_EMB 512
#define NM (N_SPK * M_UTT)
#define FP8_SCALE 16.0f   // quantization scale for fp8 operands (1/256 folded into w)

typedef __attribute__((ext_vector_type(4))) float f32x4;
typedef __attribute__((ext_vector_type(4))) int   i32x4;
typedef __attribute__((ext_vector_type(8))) int   i32x8;

__device__ __forceinline__ void async_copy16(const void* g, void* l) {
    __builtin_amdgcn_global_load_lds(
        (const __attribute__((address_space(1))) unsigned int*)g,
        (__attribute__((address_space(3))) unsigned int*)l,
        16, 0, 0);
}

// read one 32B (K=128) MFMA fragment from swizzled LDS: granule 2q of row r at
// slot s0 = 2q ^ (r&7), granule 2q+1 at s0^1. base points at the 128B row.
__device__ __forceinline__ i32x8 ld_frag(const unsigned char* base, int s0) {
    i32x4 lo = *(const i32x4*)(base + s0 * 16);
    i32x4 hi = *(const i32x4*)(base + (s0 ^ 1) * 16);
    return __builtin_shufflevector(lo, hi, 0, 1, 2, 3, 4, 5, 6, 7);
}

// ---------------------------------------------------------------------------
// Kernel A: per-speaker prep (round-7 34KB-LDS version, unchanged).
// ---------------------------------------------------------------------------
__global__ __launch_bounds__(256) void prep_kernel(
    const float* __restrict__ V, const float* __restrict__ wp,
    const float* __restrict__ bp, unsigned char* __restrict__ Cn8,
    unsigned char* __restrict__ vn8, float* __restrict__ dterm,
    float* __restrict__ colsum, float* __restrict__ out)
{
    const int spk = blockIdx.x, t = threadIdx.x;
    const int wave = t >> 6, lane = t & 63;
    const float2* vb = (const float2*)(V + (size_t)spk * (M_UTT * D_EMB)); // [16][256]

    __shared__ __align__(16) float2 red[M_UTT][264];  // {sv,vv} partials (+8 pad)
    __shared__ float red2[32];    // rows 0..15 sv, 16..31 vv
    __shared__ float invs[M_UTT];
    __shared__ float wred[4];

    // folded zeroing of colsum + out
    if (spk < 128) colsum[spk * 256 + t] = 0.f;
    if (spk == 0 && t == 0) out[0] = 0.f;

    // ---- single global read pass ----
    float2 p[M_UTT];
#pragma unroll
    for (int m = 0; m < M_UTT; ++m) p[m] = vb[m * 256 + t];

    float2 ss = make_float2(0.f, 0.f);
#pragma unroll
    for (int m = 0; m < M_UTT; ++m) { ss.x += p[m].x; ss.y += p[m].y; }

    // ||ssum||^2 butterfly (4 waves -> wred)
    float cnp = ss.x * ss.x + ss.y * ss.y;
#pragma unroll
    for (int off = 32; off > 0; off >>= 1) cnp += __shfl_xor(cnp, off);
    if (lane == 0) wred[wave] = cnp;

    // per-utterance partials -> LDS (packed sv,vv)
#pragma unroll
    for (int m = 0; m < M_UTT; ++m) {
        red[m][t] = make_float2(ss.x * p[m].x + ss.y * p[m].y,      // <ssum, v> part
                                p[m].x * p[m].x + p[m].y * p[m].y); // ||v||^2 part
    }
    __syncthreads();
    const float cn2 = wred[0] + wred[1] + wred[2] + wred[3];

    // ---- batched row reduction: 16 threads per row, 8 float4 each ----
    {
        const int r = t >> 4, s = t & 15;
        const float4* rp = (const float4*)red;   // row stride = 132 float4
        float sv = 0.f, vvs = 0.f;
#pragma unroll
        for (int k = 0; k < 8; ++k) {
            float4 q = rp[r * 132 + s + 16 * k]; // {sv0,vv0,sv1,vv1}
            sv  += q.x + q.z;
            vvs += q.y + q.w;
        }
        sv  += __shfl_xor(sv, 1);  vvs += __shfl_xor(vvs, 1);
        sv  += __shfl_xor(sv, 2);  vvs += __shfl_xor(vvs, 2);
        sv  += __shfl_xor(sv, 4);  vvs += __shfl_xor(vvs, 4);
        sv  += __shfl_xor(sv, 8);  vvs += __shfl_xor(vvs, 8);
        if (s == 0) { red2[r] = sv; red2[r + 16] = vvs; }
    }
    __syncthreads();

    // ---- per-utterance scalars (fp32-exact leave-one-out sims) ----
    if (t < M_UTT) {
        const float sv = red2[t], vv = red2[t + 16];
        const float cc = cn2 - 2.f * sv + vv;      // ||ssum - v||^2
        const float cv = sv - vv;                  // <ssum - v, v>
        const float dc = fmaxf(sqrtf(fmaxf(cc, 0.f)) * (1.f / (M_UTT - 1)), 1e-8f) * (M_UTT - 1);
        const float dv = fmaxf(sqrtf(vv), 1e-8f);
        dterm[spk * M_UTT + t] = (*wp) * (cv / (dc * dv)) + (*bp);
        invs[t] = FP8_SCALE / dv;
    }
    __syncthreads();

    // ---- fp8 outputs (x16 scale) ----
    const float cs = FP8_SCALE / (M_UTT * fmaxf(sqrtf(cn2) * (1.f / M_UTT), 1e-8f));
    {
        int pk = __builtin_amdgcn_cvt_pk_fp8_f32(ss.x * cs, ss.y * cs, 0, false);
        ((unsigned short*)(Cn8 + (size_t)spk * D_EMB))[t] = (unsigned short)pk;
    }
#pragma unroll
    for (int m = 0; m < M_UTT; ++m) {
        const float iv = invs[m];
        int pk = __builtin_amdgcn_cvt_pk_fp8_f32(p[m].x * iv, p[m].y * iv, 0, false);
        ((unsigned short*)(vn8 + ((size_t)(spk * M_UTT + m)) * D_EMB))[t] = (unsigned short)pk;
    }
}

// ---------------------------------------------------------------------------
// Kernel B: MX-scaled fp8 GEMM fused with exp(w'S+b), masking, col-reduce.
// Round-9: SAME 256x256/8-wave schedule as round 8, spill fixed:
// __launch_bounds__(512,2) resolved to a 128-VGPR cap (live ~200) ->
// accumulator spilled (WRITE 124MB, gemm 86us). Plain (512): LDS 132KB
// already limits to 1 block/CU = 2 waves/SIMD -> 256 VGPR budget, no cap.
// Structure: double-buffered 2x32KB per matrix, fully unrolled 4-step
// K-loop, counted vmcnt(8) (drain 0 only on last step), raw barriers,
// 4 MFMA phases per step under setprio(1).
// LDS rows are 128B = 8 granules of 16B; granule g of row r at slot g^(r&7).
// XCD remap: 1024 blocks, L=(p%8)*128+p/8 -> per XCD: A 1MB + B 2MB in L2.
// ---------------------------------------------------------------------------
__global__ __launch_bounds__(512) void gemm_kernel(
    const unsigned char* __restrict__ Cn8, const unsigned char* __restrict__ vn8,
    const float* __restrict__ wp, const float* __restrict__ bp,
    float* __restrict__ colsum)
{
    __shared__ __align__(16) unsigned char As[2 * 256 * 128];  // 2 x 32KB
    __shared__ __align__(16) unsigned char Bs[2 * 256 * 128];  // 2 x 32KB
    __shared__ float csum[256];

    const int tid = threadIdx.x;
    const int w = tid >> 6, l = tid & 63;

    // XCD-aware remap (1024 % 8 == 0 -> bijective)
    const int p_lin = blockIdx.x + 8 * blockIdx.y;      // [0, 1024)
    const int L_log = (p_lin & 7) * 128 + (p_lin >> 3);
    const int by = L_log & 7;     // speaker tile   [0,8)   (256 rows of Cn8)
    const int bx = L_log >> 3;    // utterance tile [0,128) (256 rows of vn8)

    const float wgt = (*wp) * (1.f / (FP8_SCALE * FP8_SCALE));
    const float bsc = *bp;

    if (tid < 256) csum[tid] = 0.f;

    // ---- staging geometry: wave w stages rows w*32..w*32+31 of both tiles.
    // Per k-step per matrix: 4 issues, each = 8 rows x 128B (64 lanes x 16B).
    // Lane L: row_local = L>>3 (0..7), slot = L&7; source granule = slot^row_local.
    const int r_l = l >> 3, sl8 = l & 7;
    const int g = sl8 ^ r_l;
    const unsigned char* Ab = Cn8 + (size_t)(by * 256 + w * 32 + r_l) * D_EMB + g * 16;
    const unsigned char* Bb = vn8 + (size_t)(bx * 256 + w * 32 + r_l) * D_EMB + g * 16;
    unsigned char* AsW0 = As + (w * 32) * 128;
    unsigned char* BsW0 = Bs + (w * 32) * 128;

    // ---- compute geometry: 2M x 4N wave grid; per wave 128x64 = 8x4 MFMA
    const int wm = w & 1, wn = w >> 1;                  // wm in 0..1, wn in 0..3
    const int l16 = l & 15, q = l >> 4;
    const int s0 = (2 * q) ^ (l & 7);
    const unsigned char* Ard0 = As + (wm * 128 + l16) * 128;
    const unsigned char* Brd0 = Bs + (wn * 64 + l16) * 128;

    f32x4 acc[8][4];
    const f32x4 z = {0.f, 0.f, 0.f, 0.f};
#pragma unroll
    for (int i = 0; i < 8; ++i)
#pragma unroll
        for (int j = 0; j < 4; ++j) acc[i][j] = z;

// stage K-step kt into LDS buffer b: 8 vm ops/thread (4 A + 4 B)
#define STAGE(kt, b) do {                                                    \
        unsigned char* aw_ = AsW0 + (b) * 32768;                             \
        unsigned char* bw_ = BsW0 + (b) * 32768;                             \
        _Pragma("unroll")                                                    \
        for (int i_ = 0; i_ < 4; ++i_) {                                     \
            async_copy16(Ab + i_ * 4096 + (kt) * 128, aw_ + i_ * 1024);      \
            async_copy16(Bb + i_ * 4096 + (kt) * 128, bw_ + i_ * 1024);      \
        } } while (0)

// one phase: 2 A-frag reads + 8 MFMAs under setprio(1)
#define PHASE(i0) do {                                                       \
        i32x8 af0_ = ld_frag(Ard_ + (i0) * 2048, s0);                        \
        i32x8 af1_ = ld_frag(Ard_ + ((i0) + 1) * 2048, s0);                  \
        __builtin_amdgcn_s_setprio(1);                                       \
        _Pragma("unroll")                                                    \
        for (int j_ = 0; j_ < 4; ++j_)                                       \
            acc[i0][j_] = __builtin_amdgcn_mfma_scale_f32_16x16x128_f8f6f4(  \
                af0_, bfr_[j_], acc[i0][j_], 0, 0, 0, 0x7F7F7F7F, 0, 0x7F7F7F7F); \
        _Pragma("unroll")                                                    \
        for (int j_ = 0; j_ < 4; ++j_)                                       \
            acc[(i0)+1][j_] = __builtin_amdgcn_mfma_scale_f32_16x16x128_f8f6f4( \
                af1_, bfr_[j_], acc[(i0)+1][j_], 0, 0, 0, 0x7F7F7F7F, 0, 0x7F7F7F7F); \
        __builtin_amdgcn_s_setprio(0);                                       \
    } while (0)

// consume LDS buffer b for one K-step: 4 bfr reads, then 4 phases of 2 rows
#define COMPUTE(b) do {                                                      \
        const unsigned char* Ard_ = Ard0 + (b) * 32768;                      \
        const unsigned char* Brd_ = Brd0 + (b) * 32768;                      \
        i32x8 bfr_[4];                                                       \
        _Pragma("unroll")                                                    \
        for (int j_ = 0; j_ < 4; ++j_) bfr_[j_] = ld_frag(Brd_ + j_ * 2048, s0); \
        PHASE(0); PHASE(2); PHASE(4); PHASE(6);                              \
    } while (0)

    // ---- prologue: 2 K-steps in flight (16 vm ops/thread outstanding)
    STAGE(0, 0);
    STAGE(1, 1);

    // step 0: wait k0 (k1's 8 stay in flight)
    asm volatile("s_waitcnt vmcnt(8)" ::: "memory");
    __builtin_amdgcn_s_barrier();
    COMPUTE(0);
    __builtin_amdgcn_s_barrier();          // all waves done reading buf0
    STAGE(2, 0);

    // step 1
    asm volatile("s_waitcnt vmcnt(8)" ::: "memory");
    __builtin_amdgcn_s_barrier();
    COMPUTE(1);
    __builtin_amdgcn_s_barrier();          // all waves done reading buf1
    STAGE(3, 1);

    // step 2
    asm volatile("s_waitcnt vmcnt(8)" ::: "memory");
    __builtin_amdgcn_s_barrier();
    COMPUTE(0);
    // buf0 not reused -> no trailing barrier

    // step 3: drain
    asm volatile("s_waitcnt vmcnt(0)" ::: "memory");
    __builtin_amdgcn_s_barrier();
    COMPUTE(1);

#undef STAGE
#undef PHASE
#undef COMPUTE

    // epilogue: e = exp(w'*dot+b), zero same-speaker entries, reduce over rows.
    // C/D layout (shape-determined): row = q*4 + r, col = l16.
    const int rowg0 = by * 256 + wm * 128 + q * 4;
    const int colg0 = bx * 256 + wn * 64 + l16;
#pragma unroll
    for (int j = 0; j < 4; ++j) {
        const int colg = colg0 + j * 16;
        const int cspk = colg >> 4;       // speaker owning this column
        float p = 0.f;
#pragma unroll
        for (int i = 0; i < 8; ++i) {
            const int rowg = rowg0 + i * 16;
#pragma unroll
            for (int r = 0; r < 4; ++r) {
                float e = __expf(wgt * acc[i][j][r] + bsc);
                p += (rowg + r == cspk) ? 0.f : e;
            }
        }
        p += __shfl_xor(p, 16);
        p += __shfl_xor(p, 32);
        if (q == 0) atomicAdd(&csum[wn * 64 + j * 16 + l16], p);
    }
    __syncthreads();
    if (tid < 256) atomicAdd(&colsum[bx * 256 + tid], csum[tid]);
}

// ---------------------------------------------------------------------------
// Kernel C: L_j = -dterm_j + log(colsum_j + exp(dterm_j)); sum -> out[0]
// ---------------------------------------------------------------------------
__global__ __launch_bounds__(256) void finish_kernel(
    const float* __restrict__ dterm, const float* __restrict__ colsum,
    float* __restrict__ out)
{
    const int idx = blockIdx.x * 256 + threadIdx.x;
    const int stride = gridDim.x * 256;
    float local = 0.f;
    for (int j = idx; j < NM; j += stride) {
        float t = dterm[j];
        local += logf(colsum[j] + __expf(t)) - t;
    }
#pragma unroll
    for (int off = 32; off > 0; off >>= 1) local += __shfl_xor(local, off);
    __shared__ float wr[4];
    const int wave = threadIdx.x >> 6, lane = threadIdx.x & 63;
    if (lane == 0) wr[wave] = local;
    __syncthreads();
    if (threadIdx.x == 0) atomicAdd(out, wr[0] + wr[1] + wr[2] + wr[3]);
}

extern "C" void kernel_launch(void* const* d_in, const int* in_sizes, int n_in,
                              void* d_out, int out_size, void* d_ws, size_t ws_size,
                              hipStream_t stream) {
    const float* V  = (const float*)d_in[0];
    const float* wp = (const float*)d_in[1];
    const float* bp = (const float*)d_in[2];

    char* ws = (char*)d_ws;
    unsigned char* Cn8 = (unsigned char*)ws;                        //  1 MB [2048][512] fp8
    unsigned char* vn8 = (unsigned char*)(ws + ((size_t)1 << 20));  // 16 MB [32768][512] fp8
    float* dterm  = (float*)(ws + ((size_t)17 << 20));              // 128 KB
    float* colsum = dterm + NM;                                     // 128 KB
    float* out    = (float*)d_out;

    prep_kernel<<<N_SPK, 256, 0, stream>>>(V, wp, bp, Cn8, vn8, dterm, colsum, out);
    gemm_kernel<<<dim3(8, 128), 512, 0, stream>>>(Cn8, vn8, wp, bp, colsum);
    finish_kernel<<<64, 256, 0, stream>>>(dterm, colsum, out);
}

// Round 10
// 181.289 us; speedup vs baseline: 1.0033x; 1.0033x over previous
//
#include <hip/hip_runtime.h>
#include <stdint.h>

#define N_SPK 2048
#define M_UTT 16
#define D_EMB 512
#define NM (N_SPK * M_UTT)
#define FP8_SCALE 16.0f   // quantization scale for fp8 operands (1/256 folded into w)

typedef __attribute__((ext_vector_type(4))) float f32x4;
typedef __attribute__((ext_vector_type(4))) int   i32x4;
typedef __attribute__((ext_vector_type(8))) int   i32x8;

__device__ __forceinline__ void async_copy16(const void* g, void* l) {
    __builtin_amdgcn_global_load_lds(
        (const __attribute__((address_space(1))) unsigned int*)g,
        (__attribute__((address_space(3))) unsigned int*)l,
        16, 0, 0);
}

// read one 32B (K=128) MFMA fragment from swizzled LDS: granule 2q of row r at
// slot s0 = 2q ^ (r&7), granule 2q+1 at s0^1. base points at the 128B row.
__device__ __forceinline__ i32x8 ld_frag(const unsigned char* base, int s0) {
    i32x4 lo = *(const i32x4*)(base + s0 * 16);
    i32x4 hi = *(const i32x4*)(base + (s0 ^ 1) * 16);
    return __builtin_shufflevector(lo, hi, 0, 1, 2, 3, 4, 5, 6, 7);
}

// ---------------------------------------------------------------------------
// Kernel A: per-speaker prep (round-7 34KB-LDS version, unchanged).
// ---------------------------------------------------------------------------
__global__ __launch_bounds__(256) void prep_kernel(
    const float* __restrict__ V, const float* __restrict__ wp,
    const float* __restrict__ bp, unsigned char* __restrict__ Cn8,
    unsigned char* __restrict__ vn8, float* __restrict__ dterm,
    float* __restrict__ colsum, float* __restrict__ out)
{
    const int spk = blockIdx.x, t = threadIdx.x;
    const int wave = t >> 6, lane = t & 63;
    const float2* vb = (const float2*)(V + (size_t)spk * (M_UTT * D_EMB)); // [16][256]

    __shared__ __align__(16) float2 red[M_UTT][264];  // {sv,vv} partials (+8 pad)
    __shared__ float red2[32];    // rows 0..15 sv, 16..31 vv
    __shared__ float invs[M_UTT];
    __shared__ float wred[4];

    // folded zeroing of colsum + out
    if (spk < 128) colsum[spk * 256 + t] = 0.f;
    if (spk == 0 && t == 0) out[0] = 0.f;

    // ---- single global read pass ----
    float2 p[M_UTT];
#pragma unroll
    for (int m = 0; m < M_UTT; ++m) p[m] = vb[m * 256 + t];

    float2 ss = make_float2(0.f, 0.f);
#pragma unroll
    for (int m = 0; m < M_UTT; ++m) { ss.x += p[m].x; ss.y += p[m].y; }

    // ||ssum||^2 butterfly (4 waves -> wred)
    float cnp = ss.x * ss.x + ss.y * ss.y;
#pragma unroll
    for (int off = 32; off > 0; off >>= 1) cnp += __shfl_xor(cnp, off);
    if (lane == 0) wred[wave] = cnp;

    // per-utterance partials -> LDS (packed sv,vv)
#pragma unroll
    for (int m = 0; m < M_UTT; ++m) {
        red[m][t] = make_float2(ss.x * p[m].x + ss.y * p[m].y,      // <ssum, v> part
                                p[m].x * p[m].x + p[m].y * p[m].y); // ||v||^2 part
    }
    __syncthreads();
    const float cn2 = wred[0] + wred[1] + wred[2] + wred[3];

    // ---- batched row reduction: 16 threads per row, 8 float4 each ----
    {
        const int r = t >> 4, s = t & 15;
        const float4* rp = (const float4*)red;   // row stride = 132 float4
        float sv = 0.f, vvs = 0.f;
#pragma unroll
        for (int k = 0; k < 8; ++k) {
            float4 q = rp[r * 132 + s + 16 * k]; // {sv0,vv0,sv1,vv1}
            sv  += q.x + q.z;
            vvs += q.y + q.w;
        }
        sv  += __shfl_xor(sv, 1);  vvs += __shfl_xor(vvs, 1);
        sv  += __shfl_xor(sv, 2);  vvs += __shfl_xor(vvs, 2);
        sv  += __shfl_xor(sv, 4);  vvs += __shfl_xor(vvs, 4);
        sv  += __shfl_xor(sv, 8);  vvs += __shfl_xor(vvs, 8);
        if (s == 0) { red2[r] = sv; red2[r + 16] = vvs; }
    }
    __syncthreads();

    // ---- per-utterance scalars (fp32-exact leave-one-out sims) ----
    if (t < M_UTT) {
        const float sv = red2[t], vv = red2[t + 16];
        const float cc = cn2 - 2.f * sv + vv;      // ||ssum - v||^2
        const float cv = sv - vv;                  // <ssum - v, v>
        const float dc = fmaxf(sqrtf(fmaxf(cc, 0.f)) * (1.f / (M_UTT - 1)), 1e-8f) * (M_UTT - 1);
        const float dv = fmaxf(sqrtf(vv), 1e-8f);
        dterm[spk * M_UTT + t] = (*wp) * (cv / (dc * dv)) + (*bp);
        invs[t] = FP8_SCALE / dv;
    }
    __syncthreads();

    // ---- fp8 outputs (x16 scale) ----
    const float cs = FP8_SCALE / (M_UTT * fmaxf(sqrtf(cn2) * (1.f / M_UTT), 1e-8f));
    {
        int pk = __builtin_amdgcn_cvt_pk_fp8_f32(ss.x * cs, ss.y * cs, 0, false);
        ((unsigned short*)(Cn8 + (size_t)spk * D_EMB))[t] = (unsigned short)pk;
    }
#pragma unroll
    for (int m = 0; m < M_UTT; ++m) {
        const float iv = invs[m];
        int pk = __builtin_amdgcn_cvt_pk_fp8_f32(p[m].x * iv, p[m].y * iv, 0, false);
        ((unsigned short*)(vn8 + ((size_t)(spk * M_UTT + m)) * D_EMB))[t] = (unsigned short)pk;
    }
}

// ---------------------------------------------------------------------------
// Kernel B: MX-scaled fp8 GEMM fused with exp(w'S+b), masking, col-reduce.
// Round-10: SAME 256x256/8-wave schedule; launch-bounds fixed AGAIN.
// Empirical allocator model (rounds 4/5/8/9): VGPR cap = 256 / (waves-per-EU
// arg); default (no arg) = 2 -> 128 cap -> still spilled (R9: VGPR 128,
// WRITE 124MB). (512,1) -> cap 256; live set ~200 fits, LDS (132KB) already
// limits to 1 block/CU so declaring 1 wave/EU costs nothing.
// Structure: double-buffered 2x32KB per matrix, fully unrolled 4-step
// K-loop, counted vmcnt(8) (drain 0 only on last step), raw barriers,
// 4 MFMA phases per step under setprio(1).
// LDS rows are 128B = 8 granules of 16B; granule g of row r at slot g^(r&7).
// XCD remap: 1024 blocks, L=(p%8)*128+p/8 -> per XCD: A 1MB + B 2MB in L2.
// ---------------------------------------------------------------------------
__global__ __launch_bounds__(512, 1) void gemm_kernel(
    const unsigned char* __restrict__ Cn8, const unsigned char* __restrict__ vn8,
    const float* __restrict__ wp, const float* __restrict__ bp,
    float* __restrict__ colsum)
{
    __shared__ __align__(16) unsigned char As[2 * 256 * 128];  // 2 x 32KB
    __shared__ __align__(16) unsigned char Bs[2 * 256 * 128];  // 2 x 32KB
    __shared__ float csum[256];

    const int tid = threadIdx.x;
    const int w = tid >> 6, l = tid & 63;

    // XCD-aware remap (1024 % 8 == 0 -> bijective)
    const int p_lin = blockIdx.x + 8 * blockIdx.y;      // [0, 1024)
    const int L_log = (p_lin & 7) * 128 + (p_lin >> 3);
    const int by = L_log & 7;     // speaker tile   [0,8)   (256 rows of Cn8)
    const int bx = L_log >> 3;    // utterance tile [0,128) (256 rows of vn8)

    const float wgt = (*wp) * (1.f / (FP8_SCALE * FP8_SCALE));
    const float bsc = *bp;

    if (tid < 256) csum[tid] = 0.f;

    // ---- staging geometry: wave w stages rows w*32..w*32+31 of both tiles.
    // Per k-step per matrix: 4 issues, each = 8 rows x 128B (64 lanes x 16B).
    // Lane L: row_local = L>>3 (0..7), slot = L&7; source granule = slot^row_local.
    const int r_l = l >> 3, sl8 = l & 7;
    const int g = sl8 ^ r_l;
    const unsigned char* Ab = Cn8 + (size_t)(by * 256 + w * 32 + r_l) * D_EMB + g * 16;
    const unsigned char* Bb = vn8 + (size_t)(bx * 256 + w * 32 + r_l) * D_EMB + g * 16;
    unsigned char* AsW0 = As + (w * 32) * 128;
    unsigned char* BsW0 = Bs + (w * 32) * 128;

    // ---- compute geometry: 2M x 4N wave grid; per wave 128x64 = 8x4 MFMA
    const int wm = w & 1, wn = w >> 1;                  // wm in 0..1, wn in 0..3
    const int l16 = l & 15, q = l >> 4;
    const int s0 = (2 * q) ^ (l & 7);
    const unsigned char* Ard0 = As + (wm * 128 + l16) * 128;
    const unsigned char* Brd0 = Bs + (wn * 64 + l16) * 128;

    f32x4 acc[8][4];
    const f32x4 z = {0.f, 0.f, 0.f, 0.f};
#pragma unroll
    for (int i = 0; i < 8; ++i)
#pragma unroll
        for (int j = 0; j < 4; ++j) acc[i][j] = z;

// stage K-step kt into LDS buffer b: 8 vm ops/thread (4 A + 4 B)
#define STAGE(kt, b) do {                                                    \
        unsigned char* aw_ = AsW0 + (b) * 32768;                             \
        unsigned char* bw_ = BsW0 + (b) * 32768;                             \
        _Pragma("unroll")                                                    \
        for (int i_ = 0; i_ < 4; ++i_) {                                     \
            async_copy16(Ab + i_ * 4096 + (kt) * 128, aw_ + i_ * 1024);      \
            async_copy16(Bb + i_ * 4096 + (kt) * 128, bw_ + i_ * 1024);      \
        } } while (0)

// one phase: 2 A-frag reads + 8 MFMAs under setprio(1)
#define PHASE(i0) do {                                                       \
        i32x8 af0_ = ld_frag(Ard_ + (i0) * 2048, s0);                        \
        i32x8 af1_ = ld_frag(Ard_ + ((i0) + 1) * 2048, s0);                  \
        __builtin_amdgcn_s_setprio(1);                                       \
        _Pragma("unroll")                                                    \
        for (int j_ = 0; j_ < 4; ++j_)                                       \
            acc[i0][j_] = __builtin_amdgcn_mfma_scale_f32_16x16x128_f8f6f4(  \
                af0_, bfr_[j_], acc[i0][j_], 0, 0, 0, 0x7F7F7F7F, 0, 0x7F7F7F7F); \
        _Pragma("unroll")                                                    \
        for (int j_ = 0; j_ < 4; ++j_)                                       \
            acc[(i0)+1][j_] = __builtin_amdgcn_mfma_scale_f32_16x16x128_f8f6f4( \
                af1_, bfr_[j_], acc[(i0)+1][j_], 0, 0, 0, 0x7F7F7F7F, 0, 0x7F7F7F7F); \
        __builtin_amdgcn_s_setprio(0);                                       \
    } while (0)

// consume LDS buffer b for one K-step: 4 bfr reads, then 4 phases of 2 rows
#define COMPUTE(b) do {                                                      \
        const unsigned char* Ard_ = Ard0 + (b) * 32768;                      \
        const unsigned char* Brd_ = Brd0 + (b) * 32768;                      \
        i32x8 bfr_[4];                                                       \
        _Pragma("unroll")                                                    \
        for (int j_ = 0; j_ < 4; ++j_) bfr_[j_] = ld_frag(Brd_ + j_ * 2048, s0); \
        PHASE(0); PHASE(2); PHASE(4); PHASE(6);                              \
    } while (0)

    // ---- prologue: 2 K-steps in flight (16 vm ops/thread outstanding)
    STAGE(0, 0);
    STAGE(1, 1);

    // step 0: wait k0 (k1's 8 stay in flight)
    asm volatile("s_waitcnt vmcnt(8)" ::: "memory");
    __builtin_amdgcn_s_barrier();
    COMPUTE(0);
    __builtin_amdgcn_s_barrier();          // all waves done reading buf0
    STAGE(2, 0);

    // step 1
    asm volatile("s_waitcnt vmcnt(8)" ::: "memory");
    __builtin_amdgcn_s_barrier();
    COMPUTE(1);
    __builtin_amdgcn_s_barrier();          // all waves done reading buf1
    STAGE(3, 1);

    // step 2
    asm volatile("s_waitcnt vmcnt(8)" ::: "memory");
    __builtin_amdgcn_s_barrier();
    COMPUTE(0);
    // buf0 not reused -> no trailing barrier

    // step 3: drain
    asm volatile("s_waitcnt vmcnt(0)" ::: "memory");
    __builtin_amdgcn_s_barrier();
    COMPUTE(1);

#undef STAGE
#undef PHASE
#undef COMPUTE

    // epilogue: e = exp(w'*dot+b), zero same-speaker entries, reduce over rows.
    // C/D layout (shape-determined): row = q*4 + r, col = l16.
    const int rowg0 = by * 256 + wm * 128 + q * 4;
    const int colg0 = bx * 256 + wn * 64 + l16;
#pragma unroll
    for (int j = 0; j < 4; ++j) {
        const int colg = colg0 + j * 16;
        const int cspk = colg >> 4;       // speaker owning this column
        float p = 0.f;
#pragma unroll
        for (int i = 0; i < 8; ++i) {
            const int rowg = rowg0 + i * 16;
#pragma unroll
            for (int r = 0; r < 4; ++r) {
                float e = __expf(wgt * acc[i][j][r] + bsc);
                p += (rowg + r == cspk) ? 0.f : e;
            }
        }
        p += __shfl_xor(p, 16);
        p += __shfl_xor(p, 32);
        if (q == 0) atomicAdd(&csum[wn * 64 + j * 16 + l16], p);
    }
    __syncthreads();
    if (tid < 256) atomicAdd(&colsum[bx * 256 + tid], csum[tid]);
}

// ---------------------------------------------------------------------------
// Kernel C: L_j = -dterm_j + log(colsum_j + exp(dterm_j)); sum -> out[0]
// ---------------------------------------------------------------------------
__global__ __launch_bounds__(256) void finish_kernel(
    const float* __restrict__ dterm, const float* __restrict__ colsum,
    float* __restrict__ out)
{
    const int idx = blockIdx.x * 256 + threadIdx.x;
    const int stride = gridDim.x * 256;
    float local = 0.f;
    for (int j = idx; j < NM; j += stride) {
        float t = dterm[j];
        local += logf(colsum[j] + __expf(t)) - t;
    }
#pragma unroll
    for (int off = 32; off > 0; off >>= 1) local += __shfl_xor(local, off);
    __shared__ float wr[4];
    const int wave = threadIdx.x >> 6, lane = threadIdx.x & 63;
    if (lane == 0) wr[wave] = local;
    __syncthreads();
    if (threadIdx.x == 0) atomicAdd(out, wr[0] + wr[1] + wr[2] + wr[3]);
}

extern "C" void kernel_launch(void* const* d_in, const int* in_sizes, int n_in,
                              void* d_out, int out_size, void* d_ws, size_t ws_size,
                              hipStream_t stream) {
    const float* V  = (const float*)d_in[0];
    const float* wp = (const float*)d_in[1];
    const float* bp = (const float*)d_in[2];

    char* ws = (char*)d_ws;
    unsigned char* Cn8 = (unsigned char*)ws;                        //  1 MB [2048][512] fp8
    unsigned char* vn8 = (unsigned char*)(ws + ((size_t)1 << 20));  // 16 MB [32768][512] fp8
    float* dterm  = (float*)(ws + ((size_t)17 << 20));              // 128 KB
    float* colsum = dterm + NM;                                     // 128 KB
    float* out    = (float*)d_out;

    prep_kernel<<<N_SPK, 256, 0, stream>>>(V, wp, bp, Cn8, vn8, dterm, colsum, out);
    gemm_kernel<<<dim3(8, 128), 512, 0, stream>>>(Cn8, vn8, wp, bp, colsum);
    finish_kernel<<<64, 256, 0, stream>>>(dterm, colsum, out);
}

// Round 11
// 165.141 us; speedup vs baseline: 1.1014x; 1.0978x over previous
//
#include <hip/hip_runtime.h>
#include <stdint.h>

#define N_SPK 2048
#define M_UTT 16
#define D_EMB 512
#define NM (N_SPK * M_UTT)
#define FP8_SCALE 16.0f   // quantization scale for fp8 operands (1/256 folded into w)

typedef __attribute__((ext_vector_type(4))) float f32x4;
typedef __attribute__((ext_vector_type(4))) int   i32x4;
typedef __attribute__((ext_vector_type(8))) int   i32x8;

__device__ __forceinline__ void async_copy16(const void* g, void* l) {
    __builtin_amdgcn_global_load_lds(
        (const __attribute__((address_space(1))) unsigned int*)g,
        (__attribute__((address_space(3))) unsigned int*)l,
        16, 0, 0);
}

// read one 32B (K=128) MFMA fragment from swizzled LDS: granule 2q of row r at
// slot s0 = 2q ^ (r&7), granule 2q+1 at s0^1. base points at the 128B row.
__device__ __forceinline__ i32x8 ld_frag(const unsigned char* base, int s0) {
    i32x4 lo = *(const i32x4*)(base + s0 * 16);
    i32x4 hi = *(const i32x4*)(base + (s0 ^ 1) * 16);
    return __builtin_shufflevector(lo, hi, 0, 1, 2, 3, 4, 5, 6, 7);
}

// ---------------------------------------------------------------------------
// Kernel A: per-speaker prep (round-7 34KB-LDS version, unchanged).
// ---------------------------------------------------------------------------
__global__ __launch_bounds__(256) void prep_kernel(
    const float* __restrict__ V, const float* __restrict__ wp,
    const float* __restrict__ bp, unsigned char* __restrict__ Cn8,
    unsigned char* __restrict__ vn8, float* __restrict__ dterm,
    float* __restrict__ colsum, float* __restrict__ out)
{
    const int spk = blockIdx.x, t = threadIdx.x;
    const int wave = t >> 6, lane = t & 63;
    const float2* vb = (const float2*)(V + (size_t)spk * (M_UTT * D_EMB)); // [16][256]

    __shared__ __align__(16) float2 red[M_UTT][264];  // {sv,vv} partials (+8 pad)
    __shared__ float red2[32];    // rows 0..15 sv, 16..31 vv
    __shared__ float invs[M_UTT];
    __shared__ float wred[4];

    // folded zeroing of colsum + out
    if (spk < 128) colsum[spk * 256 + t] = 0.f;
    if (spk == 0 && t == 0) out[0] = 0.f;

    // ---- single global read pass ----
    float2 p[M_UTT];
#pragma unroll
    for (int m = 0; m < M_UTT; ++m) p[m] = vb[m * 256 + t];

    float2 ss = make_float2(0.f, 0.f);
#pragma unroll
    for (int m = 0; m < M_UTT; ++m) { ss.x += p[m].x; ss.y += p[m].y; }

    // ||ssum||^2 butterfly (4 waves -> wred)
    float cnp = ss.x * ss.x + ss.y * ss.y;
#pragma unroll
    for (int off = 32; off > 0; off >>= 1) cnp += __shfl_xor(cnp, off);
    if (lane == 0) wred[wave] = cnp;

    // per-utterance partials -> LDS (packed sv,vv)
#pragma unroll
    for (int m = 0; m < M_UTT; ++m) {
        red[m][t] = make_float2(ss.x * p[m].x + ss.y * p[m].y,      // <ssum, v> part
                                p[m].x * p[m].x + p[m].y * p[m].y); // ||v||^2 part
    }
    __syncthreads();
    const float cn2 = wred[0] + wred[1] + wred[2] + wred[3];

    // ---- batched row reduction: 16 threads per row, 8 float4 each ----
    {
        const int r = t >> 4, s = t & 15;
        const float4* rp = (const float4*)red;   // row stride = 132 float4
        float sv = 0.f, vvs = 0.f;
#pragma unroll
        for (int k = 0; k < 8; ++k) {
            float4 q = rp[r * 132 + s + 16 * k]; // {sv0,vv0,sv1,vv1}
            sv  += q.x + q.z;
            vvs += q.y + q.w;
        }
        sv  += __shfl_xor(sv, 1);  vvs += __shfl_xor(vvs, 1);
        sv  += __shfl_xor(sv, 2);  vvs += __shfl_xor(vvs, 2);
        sv  += __shfl_xor(sv, 4);  vvs += __shfl_xor(vvs, 4);
        sv  += __shfl_xor(sv, 8);  vvs += __shfl_xor(vvs, 8);
        if (s == 0) { red2[r] = sv; red2[r + 16] = vvs; }
    }
    __syncthreads();

    // ---- per-utterance scalars (fp32-exact leave-one-out sims) ----
    if (t < M_UTT) {
        const float sv = red2[t], vv = red2[t + 16];
        const float cc = cn2 - 2.f * sv + vv;      // ||ssum - v||^2
        const float cv = sv - vv;                  // <ssum - v, v>
        const float dc = fmaxf(sqrtf(fmaxf(cc, 0.f)) * (1.f / (M_UTT - 1)), 1e-8f) * (M_UTT - 1);
        const float dv = fmaxf(sqrtf(vv), 1e-8f);
        dterm[spk * M_UTT + t] = (*wp) * (cv / (dc * dv)) + (*bp);
        invs[t] = FP8_SCALE / dv;
    }
    __syncthreads();

    // ---- fp8 outputs (x16 scale) ----
    const float cs = FP8_SCALE / (M_UTT * fmaxf(sqrtf(cn2) * (1.f / M_UTT), 1e-8f));
    {
        int pk = __builtin_amdgcn_cvt_pk_fp8_f32(ss.x * cs, ss.y * cs, 0, false);
        ((unsigned short*)(Cn8 + (size_t)spk * D_EMB))[t] = (unsigned short)pk;
    }
#pragma unroll
    for (int m = 0; m < M_UTT; ++m) {
        const float iv = invs[m];
        int pk = __builtin_amdgcn_cvt_pk_fp8_f32(p[m].x * iv, p[m].y * iv, 0, false);
        ((unsigned short*)(vn8 + ((size_t)(spk * M_UTT + m)) * D_EMB))[t] = (unsigned short)pk;
    }
}

// ---------------------------------------------------------------------------
// Kernel B: MX-scaled fp8 GEMM fused with exp(w'S+b), masking, col-reduce.
// Round-11: 512-thread blocks abandoned (VGPR hard-capped at 128 -> spill,
// rounds 8-10). Mechanism salvaged at 4 waves: BM=128 x BN=256 tile,
// wave-tile 64x128 (acc[4][8] + resident bfr[8]), PLAIN launch_bounds(256)
// (m98 precedent: plain 256-thr -> 164 VGPR + 64 AGPR, no spill).
// vs round-5: ds_read 1GB->786MB, staged 537->402MB, 32 MFMAs + 12 loads
// per barrier-pair (2x), 2048 blocks (half the epilogues). ~2 blocks/CU.
// Serial K-loop (proven best at 4 waves); swizzle: granule g of row r at
// slot g^(r&7), 128B rows. XCD remap (2048%8==0 bijective): per-XCD L2 set
// = 16 bx-tiles x 2MB B + 1MB A.
// ---------------------------------------------------------------------------
__global__ __launch_bounds__(256) void gemm_kernel(
    const unsigned char* __restrict__ Cn8, const unsigned char* __restrict__ vn8,
    const float* __restrict__ wp, const float* __restrict__ bp,
    float* __restrict__ colsum)
{
    __shared__ __align__(16) unsigned char As[128 * 128];  // 16KB
    __shared__ __align__(16) unsigned char Bs[256 * 128];  // 32KB
    __shared__ float csum[256];

    const int tid = threadIdx.x;
    const int w = tid >> 6, l = tid & 63;

    // XCD-aware remap (2048 % 8 == 0 -> bijective)
    const int p_lin = blockIdx.x + 16 * blockIdx.y;     // [0, 2048)
    const int L_log = (p_lin & 7) * 256 + (p_lin >> 3);
    const int by = L_log & 15;    // speaker tile   [0,16)  (128 rows of Cn8)
    const int bx = L_log >> 4;    // utterance tile [0,128) (256 rows of vn8)

    const float wgt = (*wp) * (1.f / (FP8_SCALE * FP8_SCALE));
    const float bsc = *bp;

    csum[tid] = 0.f;

    // ---- staging geometry (lane L: row_local = L>>3, slot = L&7,
    // source granule = slot ^ row_local; each issue = 8 rows x 128B).
    // A: wave w covers rows w*32..w*32+31 (4 issues).
    // B: wave w covers rows w*64..w*64+63 (8 issues).
    const int r_l = l >> 3, sl8 = l & 7;
    const int g = sl8 ^ r_l;
    const unsigned char* Ab = Cn8 + (size_t)(by * 128 + w * 32 + r_l) * D_EMB + g * 16;
    const unsigned char* Bb = vn8 + (size_t)(bx * 256 + w * 64 + r_l) * D_EMB + g * 16;
    unsigned char* AsW = As + (w * 32) * 128;
    unsigned char* BsW = Bs + (w * 64) * 128;

    // ---- compute geometry: 2M x 2N wave grid; per wave 64x128 = 4x8 MFMA
    const int wm = w & 1, wn = w >> 1;
    const int l16 = l & 15, q = l >> 4;
    const int s0 = (2 * q) ^ (l & 7);
    const unsigned char* Ard = As + (wm * 64 + l16) * 128;
    const unsigned char* Brd = Bs + (wn * 128 + l16) * 128;

    f32x4 acc[4][8];
    const f32x4 z = {0.f, 0.f, 0.f, 0.f};
#pragma unroll
    for (int i = 0; i < 4; ++i)
#pragma unroll
        for (int j = 0; j < 8; ++j) acc[i][j] = z;

    // ---- serial K loop: 4 steps of BK=128; cross-block TLP + deep ILP
#pragma unroll
    for (int t = 0; t < 4; ++t) {
        const int kk = t * 128;
#pragma unroll
        for (int i = 0; i < 4; ++i)
            async_copy16(Ab + i * 4096 + kk, AsW + i * 1024);
#pragma unroll
        for (int i = 0; i < 8; ++i)
            async_copy16(Bb + i * 4096 + kk, BsW + i * 1024);
        __syncthreads();   // vmcnt(0) drain + barrier: tile ready
        i32x8 bfr[8];
#pragma unroll
        for (int j = 0; j < 8; ++j) bfr[j] = ld_frag(Brd + j * 2048, s0);
#pragma unroll
        for (int i = 0; i < 4; ++i) {
            i32x8 af = ld_frag(Ard + i * 2048, s0);
#pragma unroll
            for (int j = 0; j < 8; ++j)
                acc[i][j] = __builtin_amdgcn_mfma_scale_f32_16x16x128_f8f6f4(
                    af, bfr[j], acc[i][j], 0, 0, 0, 0x7F7F7F7F, 0, 0x7F7F7F7F);
        }
        __syncthreads();   // all waves done reading before next stage overwrites
    }

    // epilogue: e = exp(w'*dot+b), zero same-speaker entries, reduce over rows.
    // C/D layout (shape-determined): row = q*4 + r, col = l16.
    const int rowg0 = by * 128 + wm * 64 + q * 4;
    const int colg0 = bx * 256 + wn * 128 + l16;
#pragma unroll
    for (int j = 0; j < 8; ++j) {
        const int colg = colg0 + j * 16;
        const int cspk = colg >> 4;       // speaker owning this column
        float p = 0.f;
#pragma unroll
        for (int i = 0; i < 4; ++i) {
            const int rowg = rowg0 + i * 16;
#pragma unroll
            for (int r = 0; r < 4; ++r) {
                float e = __expf(wgt * acc[i][j][r] + bsc);
                p += (rowg + r == cspk) ? 0.f : e;
            }
        }
        p += __shfl_xor(p, 16);
        p += __shfl_xor(p, 32);
        if (q == 0) atomicAdd(&csum[wn * 128 + j * 16 + l16], p);
    }
    __syncthreads();
    atomicAdd(&colsum[bx * 256 + tid], csum[tid]);
}

// ---------------------------------------------------------------------------
// Kernel C: L_j = -dterm_j + log(colsum_j + exp(dterm_j)); sum -> out[0]
// ---------------------------------------------------------------------------
__global__ __launch_bounds__(256) void finish_kernel(
    const float* __restrict__ dterm, const float* __restrict__ colsum,
    float* __restrict__ out)
{
    const int idx = blockIdx.x * 256 + threadIdx.x;
    const int stride = gridDim.x * 256;
    float local = 0.f;
    for (int j = idx; j < NM; j += stride) {
        float t = dterm[j];
        local += logf(colsum[j] + __expf(t)) - t;
    }
#pragma unroll
    for (int off = 32; off > 0; off >>= 1) local += __shfl_xor(local, off);
    __shared__ float wr[4];
    const int wave = threadIdx.x >> 6, lane = threadIdx.x & 63;
    if (lane == 0) wr[wave] = local;
    __syncthreads();
    if (threadIdx.x == 0) atomicAdd(out, wr[0] + wr[1] + wr[2] + wr[3]);
}

extern "C" void kernel_launch(void* const* d_in, const int* in_sizes, int n_in,
                              void* d_out, int out_size, void* d_ws, size_t ws_size,
                              hipStream_t stream) {
    const float* V  = (const float*)d_in[0];
    const float* wp = (const float*)d_in[1];
    const float* bp = (const float*)d_in[2];

    char* ws = (char*)d_ws;
    unsigned char* Cn8 = (unsigned char*)ws;                        //  1 MB [2048][512] fp8
    unsigned char* vn8 = (unsigned char*)(ws + ((size_t)1 << 20));  // 16 MB [32768][512] fp8
    float* dterm  = (float*)(ws + ((size_t)17 << 20));              // 128 KB
    float* colsum = dterm + NM;                                     // 128 KB
    float* out    = (float*)d_out;

    prep_kernel<<<N_SPK, 256, 0, stream>>>(V, wp, bp, Cn8, vn8, dterm, colsum, out);
    gemm_kernel<<<dim3(16, 128), 256, 0, stream>>>(Cn8, vn8, wp, bp, colsum);
    finish_kernel<<<64, 256, 0, stream>>>(dterm, colsum, out);
}